// Round 1
// baseline (1188.893 us; speedup 1.0000x reference)
//
#include <hip/hip_runtime.h>
#include <hip/hip_bf16.h>
#include <math.h>

typedef __bf16 bf16;
typedef __bf16 bf16x8 __attribute__((ext_vector_type(8)));
typedef float f32x4 __attribute__((ext_vector_type(4)));

__device__ __forceinline__ f32x4 mfma16(bf16x8 a, bf16x8 b, f32x4 c) {
    return __builtin_amdgcn_mfma_f32_16x16x32_bf16(a, b, c, 0, 0, 0);
}

// Problem constants
constexpr int Bv = 8, Cc = 192, Hh = 128, Wd = 128;
constexpr int HW = Hh * Wd;          // 16384
constexpr int NWIN = 2048;           // B * 16 * 16

// Workspace layout (bytes)
constexpr size_t OFF_XW    = 0;                               // bf16 [2048*64*192]
constexpr size_t SZ_XW     = (size_t)NWIN * 64 * 192 * 2;     // 50331648
constexpr size_t OFF_QKVWT = SZ_XW;                           // bf16 [576][192]
constexpr size_t OFF_PROJT = OFF_QKVWT + 576 * 192 * 2;       // bf16 [192][192]
constexpr size_t OFF_FC1T  = OFF_PROJT + 192 * 192 * 2;       // bf16 [768][192]
constexpr size_t OFF_FC2T  = OFF_FC1T + 768 * 192 * 2;        // bf16 [192][768]

// ---------------------------------------------------------------------------
// K0: transpose + convert weights to bf16, layout [n][k] (k contiguous)
// ---------------------------------------------------------------------------
__global__ void wconv_kernel(const float* __restrict__ qkv_w, const float* __restrict__ proj_w,
                             const float* __restrict__ fc1_w, const float* __restrict__ fc2_w,
                             bf16* __restrict__ qkvT, bf16* __restrict__ projT,
                             bf16* __restrict__ fc1T, bf16* __restrict__ fc2T) {
    int bid = blockIdx.x;
    const float* src; bf16* dst; int K, Nw, base;
    if (bid < 432)       { src = qkv_w;  dst = qkvT;  K = 192; Nw = 576; base = bid; }
    else if (bid < 576)  { src = proj_w; dst = projT; K = 192; Nw = 192; base = bid - 432; }
    else if (bid < 1152) { src = fc1_w;  dst = fc1T;  K = 192; Nw = 768; base = bid - 576; }
    else                 { src = fc2_w;  dst = fc2T;  K = 768; Nw = 192; base = bid - 1152; }
    int idx = base * 256 + threadIdx.x;
    if (idx < K * Nw) {
        int n = idx / K, k = idx % K;
        dst[idx] = (bf16)src[k * Nw + n];
    }
}

// ---------------------------------------------------------------------------
// K1: LN1 + roll(-4,-4) + window partition -> xw bf16 [win][n(64)][c(192)]
// ---------------------------------------------------------------------------
__global__ void __launch_bounds__(256) ln1win_kernel(const float* __restrict__ x,
                                                     const float* __restrict__ g1,
                                                     const float* __restrict__ b1,
                                                     bf16* __restrict__ xw) {
    __shared__ float xT[192][65];          // [c][token], pad 65 -> 2-way max
    __shared__ float part[2][4][64];
    __shared__ float mrs[2][64];
    int win = blockIdx.x;
    int b = win >> 8, wi = (win >> 4) & 15, wj = win & 15;
    int tid = threadIdx.x, wave = tid >> 6, t = tid & 63;
    int p = t >> 3, q = t & 7;
    int h = (wi * 8 + p + 4) & 127, w = (wj * 8 + q + 4) & 127;   // roll(-4): src = dst+4
    const float* xp = x + (size_t)b * 192 * HW + h * 128 + w;
    float sum = 0.f, ssq = 0.f;
    for (int i = 0; i < 48; i++) {
        int c = wave * 48 + i;
        float v = xp[(size_t)c * HW];
        xT[c][t] = v; sum += v; ssq += v * v;
    }
    part[0][wave][t] = sum; part[1][wave][t] = ssq;
    __syncthreads();
    if (tid < 64) {
        float s = 0.f, s2 = 0.f;
        for (int ww = 0; ww < 4; ww++) { s += part[0][ww][tid]; s2 += part[1][ww][tid]; }
        float mean = s * (1.f / 192.f);
        float var = s2 * (1.f / 192.f) - mean * mean;
        mrs[0][tid] = mean; mrs[1][tid] = rsqrtf(var + 1e-5f);
    }
    __syncthreads();
    bf16* op = xw + (size_t)win * 64 * 192;
    for (int it = 0; it < 48; it++) {
        int e = it * 256 + tid;
        int n = e / 192, c = e % 192;
        float v = (xT[c][n] - mrs[0][n]) * mrs[1][n] * g1[c] + b1[c];
        op[e] = (bf16)v;
    }
}

// ---------------------------------------------------------------------------
// K2: fused window attention: qkv GEMM -> bias+softmax -> PV -> proj -> x2
// one block (4 waves) per window. Writes x2 = shortcut + attn into d_out.
// ---------------------------------------------------------------------------
__global__ void __launch_bounds__(256, 2) attn_kernel(const float* __restrict__ x,
                                                      const bf16* __restrict__ xw,
                                                      const bf16* __restrict__ qkvT,
                                                      const float* __restrict__ qkv_b,
                                                      const bf16* __restrict__ projT,
                                                      const float* __restrict__ proj_b,
                                                      const float* __restrict__ rpb,
                                                      float* __restrict__ out) {
    // LDS plan (bytes): q[64][40]bf16 @0 (5120), k[64][40] @5120, vT[32][72] @10240 (4608),
    // s[64][67]f32 @14848 (17152), p[64][72] @32000 (9216), ao[64][200] @41216 (25600)
    // mo[192][68] aliases @0 (26112 <= 41216). Total 66816 -> 2 blocks/CU.
    __shared__ __align__(16) char smem[66816];
    bf16*  q_lds  = (bf16*)(smem);
    bf16*  k_lds  = (bf16*)(smem + 5120);
    bf16*  vT_lds = (bf16*)(smem + 10240);
    float* s_lds  = (float*)(smem + 14848);
    bf16*  p_lds  = (bf16*)(smem + 32000);
    bf16*  ao_lds = (bf16*)(smem + 41216);
    bf16*  mo_lds = (bf16*)(smem);

    int win = blockIdx.x;
    int b = win >> 8, wi = (win >> 4) & 15, wj = win & 15;
    int tid = threadIdx.x;
    int wv = tid >> 6, l = tid & 63, lo = l & 15, hi = l >> 4;
    int m0 = wv * 16;

    // A fragments of xw (rows m0..m0+15, K=192), reused for all heads
    const bf16x8* xwp = (const bf16x8*)(xw + (size_t)win * 64 * 192);
    bf16x8 afr[6];
#pragma unroll
    for (int kt = 0; kt < 6; kt++) afr[kt] = xwp[(m0 + lo) * 24 + kt * 4 + hi];

    const bf16x8* qkvw8 = (const bf16x8*)qkvT;
    for (int hd = 0; hd < 6; hd++) {
        // --- GEMM1: q,k,v (64 x 96) for this head ---
#pragma unroll
        for (int cg = 0; cg < 6; cg++) {
            int part = cg >> 1, ctl = cg & 1;
            int brow = part * 192 + hd * 32 + ctl * 16 + lo;
            f32x4 acc = {0.f, 0.f, 0.f, 0.f};
#pragma unroll
            for (int kt = 0; kt < 6; kt++)
                acc = mfma16(afr[kt], qkvw8[brow * 24 + kt * 4 + hi], acc);
            float bias = qkv_b[brow];
            if (part == 0) {
#pragma unroll
                for (int r = 0; r < 4; r++)
                    q_lds[(m0 + hi * 4 + r) * 40 + ctl * 16 + lo] =
                        (bf16)((acc[r] + bias) * 0.17677669529663687f);  // HD^-0.5
            } else if (part == 1) {
#pragma unroll
                for (int r = 0; r < 4; r++)
                    k_lds[(m0 + hi * 4 + r) * 40 + ctl * 16 + lo] = (bf16)(acc[r] + bias);
            } else {
#pragma unroll
                for (int r = 0; r < 4; r++)
                    vT_lds[(ctl * 16 + lo) * 72 + (m0 + hi * 4 + r)] = (bf16)(acc[r] + bias);
            }
        }
        __syncthreads();
        // --- scores = q @ k^T + rel-pos bias ---
        {
            bf16x8 a2 = *(const bf16x8*)&q_lds[(m0 + lo) * 40 + hi * 8];
#pragma unroll
            for (int ct = 0; ct < 4; ct++) {
                bf16x8 b2 = *(const bf16x8*)&k_lds[(ct * 16 + lo) * 40 + hi * 8];
                f32x4 sc = {0.f, 0.f, 0.f, 0.f};
                sc = mfma16(a2, b2, sc);
                int mk = ct * 16 + lo, i2 = mk >> 3, j2 = mk & 7;
#pragma unroll
                for (int r = 0; r < 4; r++) {
                    int nq = m0 + hi * 4 + r, i1 = nq >> 3, j1 = nq & 7;
                    int ridx = (i1 - i2 + 7) * 15 + (j1 - j2 + 7);
                    s_lds[nq * 67 + mk] = sc[r] + rpb[ridx * 6 + hd];
                }
            }
        }
        __syncthreads();
        // --- softmax, 4 threads per row ---
        {
            int row = tid >> 2, seg = tid & 3;
            const float* sr = &s_lds[row * 67 + seg * 16];
            float ev[16];
            float mx = -1e30f;
#pragma unroll
            for (int j = 0; j < 16; j++) { ev[j] = sr[j]; mx = fmaxf(mx, ev[j]); }
            mx = fmaxf(mx, __shfl_xor(mx, 1));
            mx = fmaxf(mx, __shfl_xor(mx, 2));
            float sum = 0.f;
#pragma unroll
            for (int j = 0; j < 16; j++) { ev[j] = __expf(ev[j] - mx); sum += ev[j]; }
            sum += __shfl_xor(sum, 1);
            sum += __shfl_xor(sum, 2);
            float inv = 1.f / sum;
            bf16* pr = &p_lds[row * 72 + seg * 16];
#pragma unroll
            for (int j = 0; j < 16; j++) pr[j] = (bf16)(ev[j] * inv);
        }
        __syncthreads();
        // --- PV: out(64x32) = P(64x64) @ V(64x32) ---
#pragma unroll
        for (int ct = 0; ct < 2; ct++) {
            f32x4 acc = {0.f, 0.f, 0.f, 0.f};
#pragma unroll
            for (int kt = 0; kt < 2; kt++) {
                bf16x8 a3 = *(const bf16x8*)&p_lds[(m0 + lo) * 72 + kt * 32 + hi * 8];
                bf16x8 b3 = *(const bf16x8*)&vT_lds[(ct * 16 + lo) * 72 + kt * 32 + hi * 8];
                acc = mfma16(a3, b3, acc);
            }
#pragma unroll
            for (int r = 0; r < 4; r++)
                ao_lds[(m0 + hi * 4 + r) * 200 + hd * 32 + ct * 16 + lo] = (bf16)acc[r];
        }
        __syncthreads();
    }
    // --- proj: (64x192) @ (192x192) ---
    bf16x8 a4[6];
#pragma unroll
    for (int kt = 0; kt < 6; kt++)
        a4[kt] = *(const bf16x8*)&ao_lds[(m0 + lo) * 200 + kt * 32 + hi * 8];
    const bf16x8* pw8 = (const bf16x8*)projT;
#pragma unroll
    for (int ct = 0; ct < 12; ct++) {
        int cc = ct * 16 + lo;
        f32x4 acc = {0.f, 0.f, 0.f, 0.f};
#pragma unroll
        for (int kt = 0; kt < 6; kt++)
            acc = mfma16(a4[kt], pw8[cc * 24 + kt * 4 + hi], acc);
        float pb = proj_b[cc];
#pragma unroll
        for (int r = 0; r < 4; r++)
            mo_lds[cc * 68 + m0 + hi * 4 + r] = (bf16)(acc[r] + pb);
    }
    __syncthreads();
    // --- write x2 = shortcut + attn_out (window reverse + roll(+4,+4)) ---
    size_t obase = (size_t)b * 192 * HW;
    for (int it = 0; it < 48; it++) {
        int e = it * 256 + tid;
        int c = e >> 6, t = e & 63;
        int hh = (wi * 8 + (t >> 3) + 4) & 127;
        int ww2 = (wj * 8 + (t & 7) + 4) & 127;
        size_t addr = obase + (size_t)c * HW + hh * 128 + ww2;
        out[addr] = x[addr] + (float)mo_lds[c * 68 + t];
    }
}

// ---------------------------------------------------------------------------
// K3: LN2 + fc1 + gelu + fc2 + residual, in-place on d_out (which holds x2)
// one block per 64 consecutive pixels (same b, h row)
// ---------------------------------------------------------------------------
__global__ void __launch_bounds__(256, 2) mlp_kernel(const float* __restrict__ g2,
                                                     const float* __restrict__ b2,
                                                     const bf16* __restrict__ fc1T,
                                                     const float* __restrict__ fc1_b,
                                                     const bf16* __restrict__ fc2T,
                                                     const float* __restrict__ fc2_b,
                                                     float* __restrict__ out) {
    __shared__ __align__(16) bf16 xn2[64 * 200];   // [token][c], pitch 200
    __shared__ __align__(16) bf16 hbuf[64 * 104];  // [token][h-chunk 96], pitch 104
    __shared__ __align__(16) bf16 mo[192 * 68];    // [c][token]
    __shared__ float part[2][4][64];
    __shared__ float mrs[2][64];

    int pix0 = blockIdx.x * 64;
    int b = pix0 >> 14, rem = pix0 & 16383;
    int hh = rem >> 7, w0 = rem & 127;
    int tid = threadIdx.x, wv = tid >> 6, t = tid & 63;
    int lo = t & 15, hi = t >> 4;
    int m0 = wv * 16;
    float* xrow = out + (size_t)b * 192 * HW + hh * 128 + w0;

    // Phase A: mean/var over C
    float sum = 0.f, ssq = 0.f;
    for (int i = 0; i < 48; i++) {
        int c = wv * 48 + i;
        float v = xrow[(size_t)c * HW + t];
        sum += v; ssq += v * v;
    }
    part[0][wv][t] = sum; part[1][wv][t] = ssq;
    __syncthreads();
    if (tid < 64) {
        float s = 0.f, s2 = 0.f;
        for (int ww = 0; ww < 4; ww++) { s += part[0][ww][tid]; s2 += part[1][ww][tid]; }
        float mean = s * (1.f / 192.f);
        float var = s2 * (1.f / 192.f) - mean * mean;
        mrs[0][tid] = mean; mrs[1][tid] = rsqrtf(var + 1e-5f);
    }
    __syncthreads();
    // Phase B: normalized bf16 tile (re-read x2 from L2)
    for (int i = 0; i < 48; i++) {
        int c = wv * 48 + i;
        float v = xrow[(size_t)c * HW + t];
        xn2[t * 200 + c] = (bf16)((v - mrs[0][t]) * mrs[1][t] * g2[c] + b2[c]);
    }
    __syncthreads();

    // Phase C: fc1+gelu -> hbuf chunk (96 cols), fc2 accumulate
    bf16x8 axn[6];
#pragma unroll
    for (int kt = 0; kt < 6; kt++)
        axn[kt] = *(const bf16x8*)&xn2[(m0 + lo) * 200 + kt * 32 + hi * 8];
    f32x4 oacc[12];
#pragma unroll
    for (int i = 0; i < 12; i++) oacc[i] = {0.f, 0.f, 0.f, 0.f};
    const bf16x8* f1 = (const bf16x8*)fc1T;
    const bf16x8* f2 = (const bf16x8*)fc2T;
    for (int ch = 0; ch < 8; ch++) {
#pragma unroll
        for (int ct = 0; ct < 6; ct++) {
            int nb = ch * 96 + ct * 16 + lo;
            f32x4 acc = {0.f, 0.f, 0.f, 0.f};
#pragma unroll
            for (int kt = 0; kt < 6; kt++)
                acc = mfma16(axn[kt], f1[nb * 24 + kt * 4 + hi], acc);
            float bb = fc1_b[nb];
#pragma unroll
            for (int r = 0; r < 4; r++) {
                float y = acc[r] + bb;
                float g = 0.5f * y * (1.f + erff(y * 0.70710678118f));
                hbuf[(m0 + hi * 4 + r) * 104 + ct * 16 + lo] = (bf16)g;
            }
        }
        __syncthreads();
        bf16x8 ah[3];
#pragma unroll
        for (int kt = 0; kt < 3; kt++)
            ah[kt] = *(const bf16x8*)&hbuf[(m0 + lo) * 104 + kt * 32 + hi * 8];
#pragma unroll
        for (int ct = 0; ct < 12; ct++) {
#pragma unroll
            for (int kt = 0; kt < 3; kt++)
                oacc[ct] = mfma16(ah[kt], f2[(ct * 16 + lo) * 96 + ch * 12 + kt * 4 + hi], oacc[ct]);
        }
        __syncthreads();
    }
    // Phase D: stage mlp out (col-major) for coalesced writeback
#pragma unroll
    for (int ct = 0; ct < 12; ct++) {
        int cc = ct * 16 + lo;
        float fb = fc2_b[cc];
#pragma unroll
        for (int r = 0; r < 4; r++)
            mo[cc * 68 + m0 + hi * 4 + r] = (bf16)(oacc[ct][r] + fb);
    }
    __syncthreads();
    // Phase E: out = x2 + mlp
    for (int it = 0; it < 48; it++) {
        int e = it * 256 + tid;
        int c = e >> 6, t2 = e & 63;
        size_t a = (size_t)c * HW + t2;
        xrow[a] = xrow[a] + (float)mo[c * 68 + t2];
    }
}

// ---------------------------------------------------------------------------
extern "C" void kernel_launch(void* const* d_in, const int* in_sizes, int n_in,
                              void* d_out, int out_size, void* d_ws, size_t ws_size,
                              hipStream_t stream) {
    const float* x      = (const float*)d_in[0];
    const float* g1     = (const float*)d_in[1];
    const float* b1     = (const float*)d_in[2];
    const float* qkv_w  = (const float*)d_in[3];
    const float* qkv_b  = (const float*)d_in[4];
    const float* proj_w = (const float*)d_in[5];
    const float* proj_b = (const float*)d_in[6];
    const float* rpb    = (const float*)d_in[7];
    const float* g2     = (const float*)d_in[8];
    const float* b2     = (const float*)d_in[9];
    const float* fc1_w  = (const float*)d_in[10];
    const float* fc1_b  = (const float*)d_in[11];
    const float* fc2_w  = (const float*)d_in[12];
    const float* fc2_b  = (const float*)d_in[13];
    float* out = (float*)d_out;
    char* ws = (char*)d_ws;
    bf16* xw    = (bf16*)(ws + OFF_XW);
    bf16* qkvT  = (bf16*)(ws + OFF_QKVWT);
    bf16* projT = (bf16*)(ws + OFF_PROJT);
    bf16* fc1T  = (bf16*)(ws + OFF_FC1T);
    bf16* fc2T  = (bf16*)(ws + OFF_FC2T);

    wconv_kernel<<<1728, 256, 0, stream>>>(qkv_w, proj_w, fc1_w, fc2_w, qkvT, projT, fc1T, fc2T);
    ln1win_kernel<<<2048, 256, 0, stream>>>(x, g1, b1, xw);
    attn_kernel<<<2048, 256, 0, stream>>>(x, xw, qkvT, qkv_b, projT, proj_b, rpb, out);
    mlp_kernel<<<2048, 256, 0, stream>>>(g2, b2, fc1T, fc1_b, fc2T, fc2_b, out);
}

// Round 2
// 826.441 us; speedup vs baseline: 1.4386x; 1.4386x over previous
//
#include <hip/hip_runtime.h>
#include <hip/hip_bf16.h>
#include <math.h>

typedef __bf16 bf16;
typedef __bf16 bf16x8 __attribute__((ext_vector_type(8)));
typedef float f32x4 __attribute__((ext_vector_type(4)));

__device__ __forceinline__ f32x4 mfma16(bf16x8 a, bf16x8 b, f32x4 c) {
    return __builtin_amdgcn_mfma_f32_16x16x32_bf16(a, b, c, 0, 0, 0);
}

// Problem constants
constexpr int Bv = 8, Cc = 192, Hh = 128, Wd = 128;
constexpr int HW = Hh * Wd;          // 16384
constexpr int NWIN = 2048;           // B * 16 * 16

// Workspace layout (bytes)
constexpr size_t OFF_XW    = 0;                               // bf16 [2048*64*192]
constexpr size_t SZ_XW     = (size_t)NWIN * 64 * 192 * 2;     // 50331648
constexpr size_t OFF_QKVWT = SZ_XW;                           // bf16 [576][192]
constexpr size_t OFF_PROJT = OFF_QKVWT + 576 * 192 * 2;       // bf16 [192][192]
constexpr size_t OFF_FC1T  = OFF_PROJT + 192 * 192 * 2;       // bf16 [768][192]
constexpr size_t OFF_FC2T  = OFF_FC1T + 768 * 192 * 2;        // bf16 [192][768]

// ---------------------------------------------------------------------------
// K0: transpose + convert weights to bf16, layout [n][k] (k contiguous)
// ---------------------------------------------------------------------------
__global__ void wconv_kernel(const float* __restrict__ qkv_w, const float* __restrict__ proj_w,
                             const float* __restrict__ fc1_w, const float* __restrict__ fc2_w,
                             bf16* __restrict__ qkvT, bf16* __restrict__ projT,
                             bf16* __restrict__ fc1T, bf16* __restrict__ fc2T) {
    int bid = blockIdx.x;
    const float* src; bf16* dst; int K, Nw, base;
    if (bid < 432)       { src = qkv_w;  dst = qkvT;  K = 192; Nw = 576; base = bid; }
    else if (bid < 576)  { src = proj_w; dst = projT; K = 192; Nw = 192; base = bid - 432; }
    else if (bid < 1152) { src = fc1_w;  dst = fc1T;  K = 192; Nw = 768; base = bid - 576; }
    else                 { src = fc2_w;  dst = fc2T;  K = 768; Nw = 192; base = bid - 1152; }
    int idx = base * 256 + threadIdx.x;
    if (idx < K * Nw) {
        int n = idx / K, k = idx % K;
        dst[idx] = (bf16)src[k * Nw + n];
    }
}

// ---------------------------------------------------------------------------
// K1: LN1 + roll(-4,-4) + window partition -> xw bf16 [win][n(64)][c(192)]
// ---------------------------------------------------------------------------
__global__ void __launch_bounds__(256) ln1win_kernel(const float* __restrict__ x,
                                                     const float* __restrict__ g1,
                                                     const float* __restrict__ b1,
                                                     bf16* __restrict__ xw) {
    __shared__ float xT[192][65];
    __shared__ float part[2][4][64];
    __shared__ float mrs[2][64];
    int win = blockIdx.x;
    int b = win >> 8, wi = (win >> 4) & 15, wj = win & 15;
    int tid = threadIdx.x, wave = tid >> 6, t = tid & 63;
    int p = t >> 3, q = t & 7;
    int h = (wi * 8 + p + 4) & 127, w = (wj * 8 + q + 4) & 127;
    const float* xp = x + (size_t)b * 192 * HW + h * 128 + w;
    float sum = 0.f, ssq = 0.f;
    for (int i = 0; i < 48; i++) {
        int c = wave * 48 + i;
        float v = xp[(size_t)c * HW];
        xT[c][t] = v; sum += v; ssq += v * v;
    }
    part[0][wave][t] = sum; part[1][wave][t] = ssq;
    __syncthreads();
    if (tid < 64) {
        float s = 0.f, s2 = 0.f;
        for (int ww = 0; ww < 4; ww++) { s += part[0][ww][tid]; s2 += part[1][ww][tid]; }
        float mean = s * (1.f / 192.f);
        float var = s2 * (1.f / 192.f) - mean * mean;
        mrs[0][tid] = mean; mrs[1][tid] = rsqrtf(var + 1e-5f);
    }
    __syncthreads();
    bf16* op = xw + (size_t)win * 64 * 192;
    for (int it = 0; it < 48; it++) {
        int e = it * 256 + tid;
        int n = e / 192, c = e % 192;
        float v = (xT[c][n] - mrs[0][n]) * mrs[1][n] * g1[c] + b1[c];
        op[e] = (bf16)v;
    }
}

// ---------------------------------------------------------------------------
// K2: fused window attention (unchanged this round)
// ---------------------------------------------------------------------------
__global__ void __launch_bounds__(256, 2) attn_kernel(const float* __restrict__ x,
                                                      const bf16* __restrict__ xw,
                                                      const bf16* __restrict__ qkvT,
                                                      const float* __restrict__ qkv_b,
                                                      const bf16* __restrict__ projT,
                                                      const float* __restrict__ proj_b,
                                                      const float* __restrict__ rpb,
                                                      float* __restrict__ out) {
    __shared__ __align__(16) char smem[66816];
    bf16*  q_lds  = (bf16*)(smem);
    bf16*  k_lds  = (bf16*)(smem + 5120);
    bf16*  vT_lds = (bf16*)(smem + 10240);
    float* s_lds  = (float*)(smem + 14848);
    bf16*  p_lds  = (bf16*)(smem + 32000);
    bf16*  ao_lds = (bf16*)(smem + 41216);
    bf16*  mo_lds = (bf16*)(smem);

    int win = blockIdx.x;
    int b = win >> 8, wi = (win >> 4) & 15, wj = win & 15;
    int tid = threadIdx.x;
    int wv = tid >> 6, l = tid & 63, lo = l & 15, hi = l >> 4;
    int m0 = wv * 16;

    const bf16x8* xwp = (const bf16x8*)(xw + (size_t)win * 64 * 192);
    bf16x8 afr[6];
#pragma unroll
    for (int kt = 0; kt < 6; kt++) afr[kt] = xwp[(m0 + lo) * 24 + kt * 4 + hi];

    const bf16x8* qkvw8 = (const bf16x8*)qkvT;
    for (int hd = 0; hd < 6; hd++) {
#pragma unroll
        for (int cg = 0; cg < 6; cg++) {
            int part = cg >> 1, ctl = cg & 1;
            int brow = part * 192 + hd * 32 + ctl * 16 + lo;
            f32x4 acc = {0.f, 0.f, 0.f, 0.f};
#pragma unroll
            for (int kt = 0; kt < 6; kt++)
                acc = mfma16(afr[kt], qkvw8[brow * 24 + kt * 4 + hi], acc);
            float bias = qkv_b[brow];
            if (part == 0) {
#pragma unroll
                for (int r = 0; r < 4; r++)
                    q_lds[(m0 + hi * 4 + r) * 40 + ctl * 16 + lo] =
                        (bf16)((acc[r] + bias) * 0.17677669529663687f);
            } else if (part == 1) {
#pragma unroll
                for (int r = 0; r < 4; r++)
                    k_lds[(m0 + hi * 4 + r) * 40 + ctl * 16 + lo] = (bf16)(acc[r] + bias);
            } else {
#pragma unroll
                for (int r = 0; r < 4; r++)
                    vT_lds[(ctl * 16 + lo) * 72 + (m0 + hi * 4 + r)] = (bf16)(acc[r] + bias);
            }
        }
        __syncthreads();
        {
            bf16x8 a2 = *(const bf16x8*)&q_lds[(m0 + lo) * 40 + hi * 8];
#pragma unroll
            for (int ct = 0; ct < 4; ct++) {
                bf16x8 b2 = *(const bf16x8*)&k_lds[(ct * 16 + lo) * 40 + hi * 8];
                f32x4 sc = {0.f, 0.f, 0.f, 0.f};
                sc = mfma16(a2, b2, sc);
                int mk = ct * 16 + lo, i2 = mk >> 3, j2 = mk & 7;
#pragma unroll
                for (int r = 0; r < 4; r++) {
                    int nq = m0 + hi * 4 + r, i1 = nq >> 3, j1 = nq & 7;
                    int ridx = (i1 - i2 + 7) * 15 + (j1 - j2 + 7);
                    s_lds[nq * 67 + mk] = sc[r] + rpb[ridx * 6 + hd];
                }
            }
        }
        __syncthreads();
        {
            int row = tid >> 2, seg = tid & 3;
            const float* sr = &s_lds[row * 67 + seg * 16];
            float ev[16];
            float mx = -1e30f;
#pragma unroll
            for (int j = 0; j < 16; j++) { ev[j] = sr[j]; mx = fmaxf(mx, ev[j]); }
            mx = fmaxf(mx, __shfl_xor(mx, 1));
            mx = fmaxf(mx, __shfl_xor(mx, 2));
            float sum = 0.f;
#pragma unroll
            for (int j = 0; j < 16; j++) { ev[j] = __expf(ev[j] - mx); sum += ev[j]; }
            sum += __shfl_xor(sum, 1);
            sum += __shfl_xor(sum, 2);
            float inv = 1.f / sum;
            bf16* pr = &p_lds[row * 72 + seg * 16];
#pragma unroll
            for (int j = 0; j < 16; j++) pr[j] = (bf16)(ev[j] * inv);
        }
        __syncthreads();
#pragma unroll
        for (int ct = 0; ct < 2; ct++) {
            f32x4 acc = {0.f, 0.f, 0.f, 0.f};
#pragma unroll
            for (int kt = 0; kt < 2; kt++) {
                bf16x8 a3 = *(const bf16x8*)&p_lds[(m0 + lo) * 72 + kt * 32 + hi * 8];
                bf16x8 b3 = *(const bf16x8*)&vT_lds[(ct * 16 + lo) * 72 + kt * 32 + hi * 8];
                acc = mfma16(a3, b3, acc);
            }
#pragma unroll
            for (int r = 0; r < 4; r++)
                ao_lds[(m0 + hi * 4 + r) * 200 + hd * 32 + ct * 16 + lo] = (bf16)acc[r];
        }
        __syncthreads();
    }
    bf16x8 a4[6];
#pragma unroll
    for (int kt = 0; kt < 6; kt++)
        a4[kt] = *(const bf16x8*)&ao_lds[(m0 + lo) * 200 + kt * 32 + hi * 8];
    const bf16x8* pw8 = (const bf16x8*)projT;
#pragma unroll
    for (int ct = 0; ct < 12; ct++) {
        int cc = ct * 16 + lo;
        f32x4 acc = {0.f, 0.f, 0.f, 0.f};
#pragma unroll
        for (int kt = 0; kt < 6; kt++)
            acc = mfma16(a4[kt], pw8[cc * 24 + kt * 4 + hi], acc);
        float pb = proj_b[cc];
#pragma unroll
        for (int r = 0; r < 4; r++)
            mo_lds[cc * 68 + m0 + hi * 4 + r] = (bf16)(acc[r] + pb);
    }
    __syncthreads();
    size_t obase = (size_t)b * 192 * HW;
    for (int it = 0; it < 48; it++) {
        int e = it * 256 + tid;
        int c = e >> 6, t = e & 63;
        int hh = (wi * 8 + (t >> 3) + 4) & 127;
        int ww2 = (wj * 8 + (t & 7) + 4) & 127;
        size_t addr = obase + (size_t)c * HW + hh * 128 + ww2;
        out[addr] = x[addr] + (float)mo_lds[c * 68 + t];
    }
}

// ---------------------------------------------------------------------------
// K3 v2: LN2 + fc1 + gelu + fc2 + residual, in-place on d_out (holds x2).
// Waves split the N dimension (disjoint weight slices -> no redundant L2
// reads); wave-M = 64 with A cached in registers -> 24 MFMA per 6 B-loads.
// fc2 accumulated in regs across two K=384 halves through LDS hbuf.
// ---------------------------------------------------------------------------
__global__ void __launch_bounds__(256, 2) mlp_kernel(const float* __restrict__ g2,
                                                     const float* __restrict__ b2,
                                                     const bf16* __restrict__ fc1T,
                                                     const float* __restrict__ fc1_b,
                                                     const bf16* __restrict__ fc2T,
                                                     const float* __restrict__ fc2_b,
                                                     float* __restrict__ out) {
    // LDS: xn2 [64][200]bf16 @0 (25600) ; hbuf [64][392]bf16 @25600 (50176) = 75776
    // part/mrs alias @25600 (dead before hbuf use); mo [192][68] aliases @0.
    __shared__ __align__(16) char smem[75776];
    bf16*  xn2  = (bf16*)smem;                        // pitch 200
    bf16*  hbuf = (bf16*)(smem + 25600);              // pitch 392
    float* part = (float*)(smem + 25600);             // [2][4][64]
    float* mrs  = (float*)(smem + 25600 + 2048);      // [2][64]
    bf16*  mo   = (bf16*)smem;                        // [192][68]

    int pix0 = blockIdx.x * 64;
    int b = pix0 >> 14, rem = pix0 & 16383;
    int hh = rem >> 7, w0 = rem & 127;
    int tid = threadIdx.x, wv = tid >> 6, t = tid & 63;
    int lo = t & 15, hi = t >> 4;
    float* xrow = out + (size_t)b * 192 * HW + hh * 128 + w0;

    // Phase A: mean/var over C
    float sum = 0.f, ssq = 0.f;
    for (int i = 0; i < 48; i++) {
        int c = wv * 48 + i;
        float v = xrow[(size_t)c * HW + t];
        sum += v; ssq += v * v;
    }
    part[(0 * 4 + wv) * 64 + t] = sum; part[(1 * 4 + wv) * 64 + t] = ssq;
    __syncthreads();
    if (tid < 64) {
        float s = 0.f, s2 = 0.f;
        for (int ww = 0; ww < 4; ww++) { s += part[ww * 64 + tid]; s2 += part[(4 + ww) * 64 + tid]; }
        float mean = s * (1.f / 192.f);
        float var = s2 * (1.f / 192.f) - mean * mean;
        mrs[tid] = mean; mrs[64 + tid] = rsqrtf(var + 1e-5f);
    }
    __syncthreads();
    // Phase B: normalized bf16 tile
    for (int i = 0; i < 48; i++) {
        int c = wv * 48 + i;
        float v = xrow[(size_t)c * HW + t];
        xn2[t * 200 + c] = (bf16)((v - mrs[t]) * mrs[64 + t] * g2[c] + b2[c]);
    }
    __syncthreads();

    // Cache ALL A-fragments for this wave (full 64 rows x K=192): 24 x bf16x8
    bf16x8 axn[4][6];
#pragma unroll
    for (int mt = 0; mt < 4; mt++)
#pragma unroll
        for (int kt = 0; kt < 6; kt++)
            axn[mt][kt] = *(const bf16x8*)&xn2[(mt * 16 + lo) * 200 + kt * 32 + hi * 8];

    f32x4 oacc[3][4];
#pragma unroll
    for (int ct = 0; ct < 3; ct++)
#pragma unroll
        for (int mt = 0; mt < 4; mt++) oacc[ct][mt] = {0.f, 0.f, 0.f, 0.f};

    const bf16x8* f1 = (const bf16x8*)fc1T;   // [768][24]
    const bf16x8* f2 = (const bf16x8*)fc2T;   // [192][96]

    for (int hf = 0; hf < 2; hf++) {
        // --- fc1 + gelu: this wave's 96-col slice of the 384-col half ---
#pragma unroll
        for (int ct = 0; ct < 6; ct++) {
            int nb = hf * 384 + wv * 96 + ct * 16 + lo;
            f32x4 acc[4];
#pragma unroll
            for (int mt = 0; mt < 4; mt++) acc[mt] = {0.f, 0.f, 0.f, 0.f};
#pragma unroll
            for (int kt = 0; kt < 6; kt++) {
                bf16x8 bfr = f1[nb * 24 + kt * 4 + hi];
#pragma unroll
                for (int mt = 0; mt < 4; mt++)
                    acc[mt] = mfma16(axn[mt][kt], bfr, acc[mt]);
            }
            float bb = fc1_b[nb];
            int col = wv * 96 + ct * 16 + lo;
#pragma unroll
            for (int mt = 0; mt < 4; mt++)
#pragma unroll
                for (int r = 0; r < 4; r++) {
                    float y = acc[mt][r] + bb;
                    float g = 0.5f * y * (1.f + erff(y * 0.70710678118f));
                    hbuf[(mt * 16 + hi * 4 + r) * 392 + col] = (bf16)g;
                }
        }
        __syncthreads();
        // --- fc2 partial over K = hf*384..+384; wave owns 48 output cols ---
#pragma unroll
        for (int kt = 0; kt < 12; kt++) {
            bf16x8 afr[4];
#pragma unroll
            for (int mt = 0; mt < 4; mt++)
                afr[mt] = *(const bf16x8*)&hbuf[(mt * 16 + lo) * 392 + kt * 32 + hi * 8];
            bf16x8 bfr[3];
#pragma unroll
            for (int ct = 0; ct < 3; ct++) {
                int cc = wv * 48 + ct * 16 + lo;
                bfr[ct] = f2[cc * 96 + hf * 48 + kt * 4 + hi];
            }
#pragma unroll
            for (int ct = 0; ct < 3; ct++)
#pragma unroll
                for (int mt = 0; mt < 4; mt++)
                    oacc[ct][mt] = mfma16(afr[mt], bfr[ct], oacc[ct][mt]);
        }
        __syncthreads();
    }

    // Phase D: stage mlp out (col-major) for coalesced writeback
#pragma unroll
    for (int ct = 0; ct < 3; ct++) {
        int cc = wv * 48 + ct * 16 + lo;
        float fb = fc2_b[cc];
#pragma unroll
        for (int mt = 0; mt < 4; mt++)
#pragma unroll
            for (int r = 0; r < 4; r++)
                mo[cc * 68 + mt * 16 + hi * 4 + r] = (bf16)(oacc[ct][mt][r] + fb);
    }
    __syncthreads();
    // Phase E: out = x2 + mlp
    for (int it = 0; it < 48; it++) {
        int e = it * 256 + tid;
        int c = e >> 6, t2 = e & 63;
        size_t a = (size_t)c * HW + t2;
        xrow[a] = xrow[a] + (float)mo[c * 68 + t2];
    }
}

// ---------------------------------------------------------------------------
extern "C" void kernel_launch(void* const* d_in, const int* in_sizes, int n_in,
                              void* d_out, int out_size, void* d_ws, size_t ws_size,
                              hipStream_t stream) {
    const float* x      = (const float*)d_in[0];
    const float* g1     = (const float*)d_in[1];
    const float* b1     = (const float*)d_in[2];
    const float* qkv_w  = (const float*)d_in[3];
    const float* qkv_b  = (const float*)d_in[4];
    const float* proj_w = (const float*)d_in[5];
    const float* proj_b = (const float*)d_in[6];
    const float* rpb    = (const float*)d_in[7];
    const float* g2     = (const float*)d_in[8];
    const float* b2     = (const float*)d_in[9];
    const float* fc1_w  = (const float*)d_in[10];
    const float* fc1_b  = (const float*)d_in[11];
    const float* fc2_w  = (const float*)d_in[12];
    const float* fc2_b  = (const float*)d_in[13];
    float* out = (float*)d_out;
    char* ws = (char*)d_ws;
    bf16* xw    = (bf16*)(ws + OFF_XW);
    bf16* qkvT  = (bf16*)(ws + OFF_QKVWT);
    bf16* projT = (bf16*)(ws + OFF_PROJT);
    bf16* fc1T  = (bf16*)(ws + OFF_FC1T);
    bf16* fc2T  = (bf16*)(ws + OFF_FC2T);

    wconv_kernel<<<1728, 256, 0, stream>>>(qkv_w, proj_w, fc1_w, fc2_w, qkvT, projT, fc1T, fc2T);
    ln1win_kernel<<<2048, 256, 0, stream>>>(x, g1, b1, xw);
    attn_kernel<<<2048, 256, 0, stream>>>(x, xw, qkvT, qkv_b, projT, proj_b, rpb, out);
    mlp_kernel<<<2048, 256, 0, stream>>>(g2, b2, fc1T, fc1_b, fc2T, fc2_b, out);
}